// Round 8
// baseline (114.356 us; speedup 1.0000x reference)
//
#include <hip/hip_runtime.h>

// SSM DPLR kernel: K[h,l] = 2*Re(C_h . dA_h^l . dB_h), dA = diag(g) + q r^T.
// R11: BARRIER-FREE CHAIN. One wave holds ALL of M64 (64 rows, 128 VGPR) and
// runs the 31-step C-chain wave-locally (readlane + FMA, no LDS, no syncs).
// Rationale: R10 proved the spill harmless (traffic normalized, time flat) and
// killed the per-step model (16 steps == 31 steps in time) -> the cost is the
// 16-wave lockstep barrier structure, not the steps. R11: 6 barriers total.
//   - 512 threads (8 waves), grid 256, amdgpu_waves_per_eu(2,2) -> VGPR cap 256
//     (demand ~170; R8/R9 lesson: pin exactly, min-only doesn't work)
//   - all Mk[] indexing compile-time (R10 lesson: runtime idx -> scratch)
//   - single M64 chain (R5-verified formulas): Cs[i] = C . M64^i, i=0..31
//   - wave0: tau-solve + Horner(T64,T64'); wave1: sigma-solve + X rebuild;
//     wave2: division prep during serial window, then M finish + chain.

#define LL 2048

struct C2 { float re, im; };

__device__ __forceinline__ C2 cmul(C2 a, C2 b){ return {a.re*b.re - a.im*b.im, a.re*b.im + a.im*b.re}; }
__device__ __forceinline__ C2 cadd(C2 a, C2 b){ return {a.re+b.re, a.im+b.im}; }
__device__ __forceinline__ C2 csub(C2 a, C2 b){ return {a.re-b.re, a.im-b.im}; }
__device__ __forceinline__ C2 cinv(C2 a){ float s=1.0f/(a.re*a.re+a.im*a.im); return {a.re*s, -a.im*s}; }
__device__ __forceinline__ C2 cscale(float s, C2 a){ return {s*a.re, s*a.im}; }
__device__ __forceinline__ C2 ld2(float2 v){ return {v.x, v.y}; }
__device__ __forceinline__ float2 st2(C2 v){ return make_float2(v.re, v.im); }

template<int CTRL>
__device__ __forceinline__ float dpp_add(float x){
  int t = __builtin_amdgcn_update_dpp(0, __float_as_int(x), CTRL, 0xF, 0xF, true);
  return x + __int_as_float(t);
}
// lane 63 ends with the full 64-lane sum
__device__ __forceinline__ float wave_sum63(float x){
  x = dpp_add<0xB1>(x);   // quad_perm xor1
  x = dpp_add<0x4E>(x);   // quad_perm xor2
  x = dpp_add<0x124>(x);  // row_ror:4
  x = dpp_add<0x128>(x);  // row_ror:8
  x = dpp_add<0x142>(x);  // row_bcast:15
  x = dpp_add<0x143>(x);  // row_bcast:31
  return x;
}
__device__ __forceinline__ float bcast63(float x){
  return __int_as_float(__builtin_amdgcn_readlane(__float_as_int(x), 63));
}
__device__ __forceinline__ float rdlane(float v, int l){
  return __int_as_float(__builtin_amdgcn_readlane(__float_as_int(v), l));
}
// D[m] = S[m-1], lane0 <- 0   (wave_shr:1 = 0x138)
__device__ __forceinline__ float shr1(float x){
  return __int_as_float(__builtin_amdgcn_update_dpp(0, __float_as_int(x), 0x138, 0xF, 0xF, true));
}

// 2-wide triangular-Toeplitz solve (length 64): v_j = rhs_j + sum_{i<j} w_{j-1-i} v_i.
__device__ __forceinline__ void tri_solve64(const C2 wl, C2 va, const int lane,
                                            float& so_re, float& so_im)
{
    C2 wsh = { shr1(wl.re), shr1(wl.im) };      // w_{m-1}, lane0 = 0
    const float w0r = rdlane(wl.re, 0);
    const float w0i = rdlane(wl.im, 0);
    so_re = 0.0f; so_im = 0.0f;
    for (int j = 0; j < 64; j += 2) {
        const float s0r = rdlane(va.re, j);
        const float s0i = rdlane(va.im, j);
        const float v1r = rdlane(va.re, j + 1);
        const float v1i = rdlane(va.im, j + 1);
        const float s1r = v1r + (w0r*s0r - w0i*s0i);
        const float s1i = v1i + (w0r*s0i + w0i*s0r);
        if (lane == j)     { so_re = s0r; so_im = s0i; }
        if (lane == j + 1) { so_re = s1r; so_im = s1i; }
        const C2 wsh1 = { shr1(wsh.re), shr1(wsh.im) };   // w_{m-2-j}
        va.re += wsh.re*s0r - wsh.im*s0i;
        va.im += wsh.re*s0i + wsh.im*s0r;
        va.re += wsh1.re*s1r - wsh1.im*s1i;
        va.im += wsh1.re*s1i + wsh1.im*s1r;
        wsh.re = shr1(wsh1.re);
        wsh.im = shr1(wsh1.im);
    }
}

__global__ __launch_bounds__(512)
__attribute__((amdgpu_waves_per_eu(2, 2)))
void ssm_dplr_kernel(
    const float* __restrict__ A_real, const float* __restrict__ A_imag,
    const float* __restrict__ B_real, const float* __restrict__ B_imag,
    const float* __restrict__ P_real, const float* __restrict__ P_imag,
    const float* __restrict__ C_real, const float* __restrict__ C_imag,
    const float* __restrict__ log_dt, float* __restrict__ out)
{
    const int h    = blockIdx.x;
    const int t    = threadIdx.x;
    const int lane = t & 63;
    const int wid  = t >> 6;         // wave 0..7

    extern __shared__ char sm[];
    float2* Abuf = (float2*)sm;               // 64x64: G (powers), later X  [32 KB]
    float2* Cs   = (float2*)(sm + 32768);     // 32x64 Y rows                [16 KB]
    // transpose-sum partials alias Cs (dead at that phase):
    float2* tw   = Cs;                        // 8x64
    float2* ta   = Cs + 512;                  // 8x64
    float2* gA   = (float2*)(sm + 49152);     // smalls, 64 float2 each:
    float2* qA   = gA + 64;
    float2* g64A = gA + 128;
    float2* TgA  = gA + 192;   // T64(g)
    float2* TpA  = gA + 256;   // T64'(g)
    float2* rqA  = gA + 320;
    float2* rxA  = gA + 384;
    float2* wvA  = gA + 448;   // w_0..63
    float2* avA  = gA + 512;   // a_0..63
    // LDS total: 49152 + 9*512 = 53760 B

    // ---------------- setup (every wave redundantly, per-lane n = lane) ----------------
    const int idx = h * 64 + lane;
    const float dt = expf(log_dt[h]);
    const float c  = 0.5f * dt;

    const C2 lam = { -A_real[idx], -A_imag[idx] };
    const C2 p   = {  P_real[idx],  P_imag[idx] };
    const C2 Bv  = {  B_real[idx],  B_imag[idx] };
    const C2 Cv  = {  C_real[idx],  C_imag[idx] };
    const C2 pc  = { p.re, -p.im };

    const C2 d = cinv(C2{ 1.0f - c*lam.re, -c*lam.im });
    const C2 g = cmul(d, C2{ 1.0f + c*lam.re, c*lam.im });   // diag of dA

    // Sherman-Morrison scalars via DPP wave sums
    C2 sv = cscale(p.re*p.re + p.im*p.im, d);
    C2 uv = cmul(cmul(d, pc), Bv);
    sv.re = bcast63(wave_sum63(sv.re)); sv.im = bcast63(wave_sum63(sv.im));
    uv.re = bcast63(wave_sum63(uv.re)); uv.im = bcast63(wave_sum63(uv.im));

    const C2 beta  = cscale(c, cinv(C2{ 1.0f + c*sv.re, c*sv.im }));
    const C2 bs    = cmul(beta, sv);
    const C2 gamma = { -c*(1.0f - bs.re), c*bs.im };

    const C2 q  = cmul(d, p);
    const C2 r  = cmul(pc, csub(gamma, cmul(beta, g)));
    const C2 x0 = cscale(dt, csub(cmul(d, Bv), cmul(cmul(beta, uv), q)));  // dB

    // power chain
    const C2 g2  = cmul(g,  g);
    const C2 g4  = cmul(g2, g2);
    const C2 g8  = cmul(g4, g4);
    const C2 g16 = cmul(g8, g8);
    const C2 g32 = cmul(g16,g16);
    const C2 g64 = cmul(g32,g32);

    if (wid == 0) {
        gA[lane]   = st2(g);
        qA[lane]   = st2(q);
        g64A[lane] = st2(g64);
        rqA[lane]  = st2(cmul(r, q));
        rxA[lane]  = st2(cmul(r, x0));
    }
    __syncthreads();

    // ---------------- G-gen: G[j][n] = g_n^j, rows j in [8w, 8w+8) ----------------
    {
        C2 cur = {1.0f, 0.0f};
        if (wid & 1) cur = g8;
        if (wid & 2) cur = cmul(cur, g16);
        if (wid & 4) cur = cmul(cur, g32);          // g^(8*wid)
        #pragma unroll
        for (int jj = 0; jj < 8; ++jj) {
            const int j = 8*wid + jj;
            Abuf[j*64 + ((lane + j) & 63)] = st2(cur);   // rotated columns
            cur = cmul(cur, g);
        }
    }
    __syncthreads();

    // ---------------- w_j, a_j via transpose-sum (lane = j) ----------------
    {
        C2 accw = {0,0}, acca = {0,0};
        #pragma unroll
        for (int kk = 0; kk < 8; ++kk) {
            const int n = 8*wid + kk;
            const C2 Gv = ld2(Abuf[lane*64 + ((n + lane) & 63)]);
            const C2 fq = ld2(rqA[n]);      // uniform
            const C2 fx = ld2(rxA[n]);      // uniform
            accw = cadd(accw, cmul(Gv, fq));
            acca = cadd(acca, cmul(Gv, fx));
        }
        tw[wid*64 + lane] = st2(accw);
        ta[wid*64 + lane] = st2(acca);
    }
    __syncthreads();
    if (t < 64) {
        C2 sw = {0,0}, sa = {0,0};
        #pragma unroll
        for (int w2 = 0; w2 < 8; ++w2) {
            sw = cadd(sw, ld2(tw[w2*64 + t]));
            sa = cadd(sa, ld2(ta[w2*64 + t]));
        }
        wvA[t] = st2(sw);
        avA[t] = st2(sa);
    }
    __syncthreads();

    // ---------------- serial window ----------------
    // wave0: tau-solve + Horner -> T64(g), T64'(g)
    // wave1: sigma-solve + X rebuild into Abuf (G is dead now)
    // wave2: division prep for M rows (needs only g) -> Mk[k] = 1/(g_k - g)
    C2 Mk[64];
    if (wid == 0) {
        const C2 wl = ld2(wvA[lane]);
        float tau_re, tau_im;
        tri_solve64(wl, wl, lane, tau_re, tau_im);      // rhs = w -> tau
        // T(z) = sum_{i=0}^{62} tau_i z^{63-i} = z * P(z); P, P' by Horner
        C2 pp = { rdlane(tau_re, 0), rdlane(tau_im, 0) };
        C2 dd = {0,0};
        for (int i = 1; i <= 62; ++i) {
            const C2 ti = { rdlane(tau_re, i), rdlane(tau_im, i) };
            dd = cadd(cmul(dd, g), pp);
            pp = cadd(cmul(pp, g), ti);
        }
        TgA[lane] = st2(cmul(g, pp));              // T(g)
        TpA[lane] = st2(cadd(pp, cmul(g, dd)));    // T'(g) = P + z P'
    } else if (wid == 1) {
        const C2 wl = ld2(wvA[lane]);
        float sg_re, sg_im;
        tri_solve64(wl, ld2(avA[lane]), lane, sg_re, sg_im);   // rhs = a -> sigma
        // X_0 = dB; X_{j+1} = g.*X_j + sigma_j * q
        C2 x = x0;
        for (int j = 0; j < 64; ++j) {
            Abuf[j*64 + ((lane + j) & 63)] = st2(x);
            const float sjr = rdlane(sg_re, j);
            const float sji = rdlane(sg_im, j);
            const float nr = g.re*x.re - g.im*x.im + sjr*q.re - sji*q.im;
            const float ni = g.re*x.im + g.im*x.re + sjr*q.im + sji*q.re;
            x.re = nr; x.im = ni;
        }
    } else if (wid == 2) {
        #pragma unroll
        for (int k = 0; k < 64; ++k) {
            const C2 gn = ld2(gA[k]);              // uniform
            Mk[k] = cinv(csub(gn, g));             // k==lane -> inf/NaN, deselected below
        }
    }
    __syncthreads();

    // ---------------- wave2: M finish + 31-step chain (NO barriers) ----------------
    // M[k][m] = d_km g64_k + q_k r_m [ (g64_k - g64_m) + (T(g_k) - T(g_m)) ] / (g_k - g_m)
    // M[k][k] = g64_k + q_k r_k ( 64 g_k^63 + T'(g_k) )
    // Lane m holds column m of M in Mk[64]; all indices compile-time.
    if (wid == 2) {
        const C2 Tgm = ld2(TgA[lane]);
        const C2 Tp  = ld2(TpA[lane]);
        const C2 g63 = cmul(g64, cinv(g));
        const C2 S   = cmul(r, cadd(cscale(64.0f, g63), Tp));
        const C2 diagv = cadd(g64, cmul(q, S));    // value for M[lane][lane]
        #pragma unroll
        for (int k = 0; k < 64; ++k) {
            const C2 qn   = ld2(qA[k]);            // uniform reads
            const C2 g64n = ld2(g64A[k]);
            const C2 Tgn  = ld2(TgA[k]);
            const C2 num  = cmul(r, cadd(csub(g64n, g64), csub(Tgn, Tgm)));
            const C2 off  = cmul(cmul(qn, num), Mk[k]);
            const bool isd = (lane == k);          // k compile-time
            Mk[k].re = isd ? diagv.re : off.re;
            Mk[k].im = isd ? diagv.im : off.im;
        }
        // chain: Cs[i] = C . M^i  (wave-local: readlane + FMA, split accumulators)
        C2 Ci = Cv;
        Cs[lane] = st2(Ci);
        for (int i = 1; i < 32; ++i) {
            float ar0 = 0.0f, ai0 = 0.0f, ar1 = 0.0f, ai1 = 0.0f;
            #pragma unroll
            for (int k = 0; k < 64; k += 2) {
                const float c0r = rdlane(Ci.re, k);
                const float c0i = rdlane(Ci.im, k);
                const float c1r = rdlane(Ci.re, k + 1);
                const float c1i = rdlane(Ci.im, k + 1);
                ar0 += c0r*Mk[k].re   - c0i*Mk[k].im;
                ai0 += c0r*Mk[k].im   + c0i*Mk[k].re;
                ar1 += c1r*Mk[k+1].re - c1i*Mk[k+1].im;
                ai1 += c1r*Mk[k+1].im + c1i*Mk[k+1].re;
            }
            Ci.re = ar0 + ar1;
            Ci.im = ai0 + ai1;
            Cs[i*64 + lane] = st2(Ci);
        }
    }
    __syncthreads();

    // ---------------- output: rows r = 4*wid + rr ----------------
    {
        float accK[4] = {0.0f, 0.0f, 0.0f, 0.0f};
        #pragma unroll 8
        for (int n = 0; n < 64; ++n) {
            const float2 xv = Abuf[lane*64 + ((n + lane) & 63)];
            #pragma unroll
            for (int rr = 0; rr < 4; ++rr) {
                const float2 cv = Cs[(4*wid + rr)*64 + n];   // uniform
                accK[rr] += cv.x*xv.x - cv.y*xv.y;
            }
        }
        float* outh = out + h * LL;
        #pragma unroll
        for (int rr = 0; rr < 4; ++rr) {
            outh[(4*wid + rr)*64 + lane] = 2.0f * accK[rr];
        }
    }
}

extern "C" void kernel_launch(void* const* d_in, const int* in_sizes, int n_in,
                              void* d_out, int out_size, void* d_ws, size_t ws_size,
                              hipStream_t stream) {
    const float* A_real = (const float*)d_in[0];
    const float* A_imag = (const float*)d_in[1];
    const float* B_real = (const float*)d_in[2];
    const float* B_imag = (const float*)d_in[3];
    const float* P_real = (const float*)d_in[4];
    const float* P_imag = (const float*)d_in[5];
    const float* C_real = (const float*)d_in[6];
    const float* C_imag = (const float*)d_in[7];
    const float* log_dt = (const float*)d_in[8];
    float* out = (float*)d_out;

    const size_t lds = 49152 + 9*64*sizeof(float2);   // 53760 B
    ssm_dplr_kernel<<<256, 512, lds, stream>>>(
        A_real, A_imag, B_real, B_imag, P_real, P_imag,
        C_real, C_imag, log_dt, out);
}